// Round 4
// baseline (9074.475 us; speedup 1.0000x reference)
//
#include <hip/hip_runtime.h>
#include <hip/hip_bf16.h>

// ---- problem sizes ----
#define UNITS 1024
#define FEATS 128
#define NG    4096
#define NSTEP 383            // 256 warmup + 127 forecast
#define HS    262144         // elems per h slice (256*1024)
#define HSB   524288UL       // bytes per h slice

// ---- ws offsets (bytes) ----
// hist slices: hist(0) dedicated (written t=255, before the global sync).
// hist(1..127) are written at t>=256, AFTER the global 256-block barrier at
// t==256 — by then x/WhR/WiR/WfR are dead, so they overlay those regions.
#define OX   0UL             // x bf16 [256][256][128]          16,777,216  (hist 1..32)
#define OWH  16777216UL      // WhR [4096][1024] bf16            8,388,608  (hist 33..48)
#define OWI  25165824UL      // WiR [4096][128] bf16             1,048,576  (hist 49..50)
#define OWF  26214400UL      // WfR [4096][1024] bf16            8,388,608  (hist 112..127)
#define OWD  34603008UL      // WdT [128][1024] bf16               262,144
#define OBR  34865152UL      // bias_r [4096] f32                   16,384
#define OBF  34881536UL      // bias_f [4096] f32                   16,384
#define OH0  34897920UL      // hist(0)                            524,288
#define OHP  35422208UL      // hp0, hp1                         1,048,576
#define OHC  36470784UL      // dedicated hist 51..111 (61)     31,981,568
#define OCNT 68452352UL      // sync counters                        1,024

typedef __attribute__((ext_vector_type(8))) short bf16x8;
typedef __attribute__((ext_vector_type(4))) float f32x4;
typedef __attribute__((address_space(3))) char lds_char;
typedef __attribute__((address_space(1))) const char glb_char;

__device__ __forceinline__ void gload_lds16(const void* g, void* l) {
    __builtin_amdgcn_global_load_lds((glb_char*)g, (lds_char*)l, 16, 0, 0);
}
#define CFENCE asm volatile("" ::: "memory")
#define SBAR   do { CFENCE; __builtin_amdgcn_s_barrier(); CFENCE; } while (0)

__device__ __forceinline__ float sigf(float x) { return 1.0f / (1.0f + __expf(-x)); }
__device__ __forceinline__ float tanh_fast(float x) { return 2.0f / (1.0f + __expf(-2.0f * x)) - 1.0f; }

__device__ __forceinline__ __hip_bfloat16* hist_ptr(char* ws, int s) {
    size_t off;
    if (s == 0)       off = OH0;
    else if (s <= 32) off = OX  + (size_t)(s - 1) * HSB;
    else if (s <= 48) off = OWH + (size_t)(s - 33) * HSB;
    else if (s <= 50) off = OWI + (size_t)(s - 49) * HSB;
    else if (s <= 111) off = OHC + (size_t)(s - 51) * HSB;
    else              off = OWF + (size_t)(s - 112) * HSB;
    return (__hip_bfloat16*)(ws + off);
}

// cross-block barrier (monotone counter, device-scope)
__device__ __forceinline__ void sync_blocks(int* c, int target) {
    __syncthreads();
    if (threadIdx.x == 0) {
        __threadfence();
        __hip_atomic_fetch_add(c, 1, __ATOMIC_RELEASE, __HIP_MEMORY_SCOPE_AGENT);
        while (__hip_atomic_load(c, __ATOMIC_ACQUIRE, __HIP_MEMORY_SCOPE_AGENT) < target)
            __builtin_amdgcn_s_sleep(8);
        __threadfence();
    }
    __syncthreads();
}

// ---------- precompute kernels ----------

__global__ void cvt_bf16(const float* __restrict__ in, __hip_bfloat16* __restrict__ out, int n) {
    int i = (blockIdx.x * blockDim.x + threadIdx.x) * 4;
    if (i >= n) return;
    float4 v = *(const float4*)(in + i);
    union { ushort4 u4; __hip_bfloat16 h[4]; } pk;
    pk.h[0] = __float2bfloat16(v.x);
    pk.h[1] = __float2bfloat16(v.y);
    pk.h[2] = __float2bfloat16(v.z);
    pk.h[3] = __float2bfloat16(v.w);
    *(ushort4*)(out + i) = pk.u4;
}

// WhR[j][k]=W_h[k][col(j)], WiR[j][q]=W_i[q][col(j)]; col(j)=(j&3)*1024 + (j>>2); read-coalesced
__global__ void build_whwi(const float* __restrict__ Wh, const float* __restrict__ Wi,
                           __hip_bfloat16* __restrict__ WhR, __hip_bfloat16* __restrict__ WiR) {
    int idx = blockIdx.x * 256 + threadIdx.x;   // 1152*4096
    int k = idx >> 12, col = idx & 4095;
    int j = ((col & 1023) << 2) | (col >> 10);
    if (k < 1024) WhR[(size_t)j * 1024 + k] = __float2bfloat16(Wh[(size_t)k * 4096 + col]);
    else          WiR[(size_t)j * 128 + (k - 1024)] = __float2bfloat16(Wi[(size_t)(k - 1024) * 4096 + col]);
}

// WdT[f][k] = W_d[k][f]  (bf16, for final p-GEMM)
__global__ void build_wd(const float* __restrict__ Wd, __hip_bfloat16* __restrict__ WdT) {
    int idx = blockIdx.x * 256 + threadIdx.x;   // 128*1024
    int f = idx >> 10, k = idx & 1023;
    WdT[(size_t)f * 1024 + k] = __float2bfloat16(Wd[(size_t)k * 128 + f]);
}

__global__ void build_bias(const float* __restrict__ b, const float* __restrict__ bd,
                           const float* __restrict__ Wi, float* __restrict__ br, float* __restrict__ bf) {
    int j = blockIdx.x * 256 + threadIdx.x;   // 4096
    int col = ((j & 3) << 10) | (j >> 2);
    float base = b[col];
    br[j] = base;
    float v = base;
    for (int q = 0; q < 128; ++q) v += bd[q] * Wi[(size_t)q * 4096 + col];
    bf[j] = v;
}

// WfR[j][k] = WhR[j][k] + sum_q WiR[j][q] * W_d[k][q]   via MFMA, 64x64 tiles, K=128
__global__ __launch_bounds__(256) void build_wf(const __hip_bfloat16* __restrict__ WhR,
                                                const __hip_bfloat16* __restrict__ WiR,
                                                const float* __restrict__ Wd,
                                                __hip_bfloat16* __restrict__ WfR) {
    const int j0 = blockIdx.x * 64, k0 = blockIdx.y * 64;
    const int tid = threadIdx.x, wave = tid >> 6, lane = tid & 63;
    const int wj = (wave >> 1) * 32, wk = (wave & 1) * 32;
    const int lr = lane & 15, lq = lane >> 4;
    f32x4 acc[2][2] = {};
    #pragma unroll
    for (int kc = 0; kc < 4; ++kc) {
        bf16x8 dfr[2], ifr[2];
        #pragma unroll
        for (int q2 = 0; q2 < 2; ++q2) {
            const float* p = Wd + (size_t)(k0 + wk + q2 * 16 + lr) * 128 + kc * 32 + lq * 8;
            __hip_bfloat16* dp = (__hip_bfloat16*)&dfr[q2];
            #pragma unroll
            for (int e = 0; e < 8; ++e) dp[e] = __float2bfloat16(p[e]);
            ifr[q2] = *(const bf16x8*)(WiR + (size_t)(j0 + wj + q2 * 16 + lr) * 128 + kc * 32 + lq * 8);
        }
        acc[0][0] = __builtin_amdgcn_mfma_f32_16x16x32_bf16(dfr[0], ifr[0], acc[0][0], 0, 0, 0);
        acc[0][1] = __builtin_amdgcn_mfma_f32_16x16x32_bf16(dfr[0], ifr[1], acc[0][1], 0, 0, 0);
        acc[1][0] = __builtin_amdgcn_mfma_f32_16x16x32_bf16(dfr[1], ifr[0], acc[1][0], 0, 0, 0);
        acc[1][1] = __builtin_amdgcn_mfma_f32_16x16x32_bf16(dfr[1], ifr[1], acc[1][1], 0, 0, 0);
    }
    #pragma unroll
    for (int cf = 0; cf < 2; ++cf)
        #pragma unroll
        for (int rf = 0; rf < 2; ++rf) {
            const int k = k0 + wk + cf * 16 + lq * 4;
            const int j = j0 + wj + rf * 16 + lr;
            const __hip_bfloat16* whp = WhR + (size_t)j * 1024 + k;
            __hip_bfloat16* wfp = WfR + (size_t)j * 1024 + k;
            #pragma unroll
            for (int e = 0; e < 4; ++e)
                wfp[e] = __float2bfloat16(acc[cf][rf][e] + __bfloat162float(whp[e]));
        }
}

// ---------- persistent LSTM kernel ----------
template<int NCH>
__device__ __forceinline__ void run_rounds(const __hip_bfloat16 (&Als)[9][32][128],
                                           const bf16x8 (&w)[4][9], f32x4 (&acc)[4][2],
                                           int lr, int lq, int kh) {
    const int cbase = kh * 4;
    #pragma unroll
    for (int r = 0; r < NCH; ++r) {
        asm volatile("s_waitcnt vmcnt(%0)" :: "i"(NCH - 1 - r) : "memory");
        __builtin_amdgcn_s_barrier();
        CFENCE;
        const int sc = (cbase + lq) ^ lr;
        const bf16x8 a0 = *(const bf16x8*)&Als[r][lr][sc * 8];
        const bf16x8 a1 = *(const bf16x8*)&Als[r][lr + 16][sc * 8];
        #pragma unroll
        for (int tc = 0; tc < 4; ++tc) {
            acc[tc][0] = __builtin_amdgcn_mfma_f32_16x16x32_bf16(w[tc][r], a0, acc[tc][0], 0, 0, 0);
            acc[tc][1] = __builtin_amdgcn_mfma_f32_16x16x32_bf16(w[tc][r], a1, acc[tc][1], 0, 0, 0);
        }
    }
}

__global__ __launch_bounds__(512, 2) void persist(char* ws) {
    const __hip_bfloat16* xb  = (const __hip_bfloat16*)(ws + OX);
    const __hip_bfloat16* whg = (const __hip_bfloat16*)(ws + OWH);
    const __hip_bfloat16* wig = (const __hip_bfloat16*)(ws + OWI);
    const __hip_bfloat16* wfg = (const __hip_bfloat16*)(ws + OWF);
    const float* brg = (const float*)(ws + OBR);
    const float* bfg = (const float*)(ws + OBF);
    __hip_bfloat16* hp0 = (__hip_bfloat16*)(ws + OHP);
    __hip_bfloat16* hp1 = hp0 + HS;
    int* cnt = (int*)(ws + OCNT);

    __shared__ __hip_bfloat16 Als[9][32][128];   // 73728 B: h/x staging, 9 K128 chunks
    __shared__ float Xl[3][2][4][2][256];        // 49152 B: K-split partial exchange

    const int bid = blockIdx.x;
    const int n0 = (bid & 31) * 128;   // gate-col tile
    const int grp = bid >> 5;          // batch group (8 groups x 32 blocks)
    const int b0 = grp * 32;
    const int tid = threadIdx.x;
    const int wave = tid >> 6, lane = tid & 63;
    const int cq = wave & 1, kh = wave >> 1;     // col 64-group, K-quarter
    const int lr = lane & 15, lq = lane >> 4;

    // weights -> registers (warmup set: Wh + Wi tail)
    bf16x8 w[4][9];
    #pragma unroll
    for (int tc = 0; tc < 4; ++tc) {
        const size_t row = (size_t)(n0 + cq * 64 + tc * 16 + lr);
        #pragma unroll
        for (int r = 0; r < 8; ++r)
            w[tc][r] = *(const bf16x8*)(whg + row * 1024 + (r * 4 + kh) * 32 + lq * 8);
        w[tc][8] = *(const bf16x8*)(wig + row * 128 + kh * 32 + lq * 8);
    }
    float4 bias[4];
    #pragma unroll
    for (int tc = 0; tc < 4; ++tc)
        bias[tc] = *(const float4*)(brg + n0 + cq * 64 + tc * 16 + lq * 4);

    float creg[4][2] = {{0.f,0.f},{0.f,0.f},{0.f,0.f},{0.f,0.f}};  // cell state, registers only

    // staging geometry (inverse-swizzled source, linear LDS dest)
    const int row_s = tid >> 4;
    const int gsw = (((tid & 15) ^ (row_s & 15)) << 3);
    const size_t soff = (size_t)(b0 + row_s) * 1024 + gsw;
    char* sdst0 = (char*)&Als[0][wave * 4][0];   // wave-uniform base

    for (int t = 0; t < NSTEP; ++t) {
        const bool fc = (t >= 256);
        const __hip_bfloat16* hsrc = fc ? hist_ptr(ws, t - 256) : ((t & 1) ? hp1 : hp0);
        __hip_bfloat16* hdst = (t >= 255) ? hist_ptr(ws, t - 255) : ((t & 1) ? hp0 : hp1);

        if (t == 256) {   // switch to folded forecast weights
            #pragma unroll
            for (int tc = 0; tc < 4; ++tc) {
                const size_t row = (size_t)(n0 + cq * 64 + tc * 16 + lr);
                #pragma unroll
                for (int r = 0; r < 8; ++r)
                    w[tc][r] = *(const bf16x8*)(wfg + row * 1024 + (r * 4 + kh) * 32 + lq * 8);
                bias[tc] = *(const float4*)(bfg + n0 + cq * 64 + tc * 16 + lq * 4);
            }
            asm volatile("s_waitcnt vmcnt(0)" ::: "memory");
            sync_blocks(cnt + 128, 256);   // all blocks loaded Wf before hist overlays can clobber
        }

        // stage all chunks of this step's A (h, + x for warmup)
        {
            const __hip_bfloat16* hsl = hsrc + soff;
            #pragma unroll
            for (int ch = 0; ch < 8; ++ch)
                gload_lds16(hsl + ch * 128, sdst0 + ch * 8192);
            if (!fc)   // x layout is [B][T][F]: batch stride 256*128
                gload_lds16(xb + (size_t)(b0 + row_s) * 32768 + (size_t)t * 128 + gsw,
                            sdst0 + 8 * 8192);
        }

        f32x4 acc[4][2] = {};
        if (!fc) run_rounds<9>(Als, w, acc, lr, lq, kh);
        else     run_rounds<8>(Als, w, acc, lr, lq, kh);

        // K-split reduction + cell update (kh==0 waves)
        if (kh != 0) {
            float* xp = &Xl[kh - 1][cq][0][0][0];
            #pragma unroll
            for (int tc = 0; tc < 4; ++tc)
                #pragma unroll
                for (int rf = 0; rf < 2; ++rf)
                    *(f32x4*)(xp + (tc * 2 + rf) * 256 + lane * 4) = acc[tc][rf];
        }
        __syncthreads();
        if (kh == 0) {
            #pragma unroll
            for (int tc = 0; tc < 4; ++tc)
                #pragma unroll
                for (int rf = 0; rf < 2; ++rf) {
                    f32x4 z = acc[tc][rf];
                    #pragma unroll
                    for (int kk = 0; kk < 3; ++kk)
                        z += *(const f32x4*)(&Xl[kk][cq][tc][rf][0] + lane * 4);
                    const float zi = z[0] + bias[tc].x;
                    const float zf = z[1] + bias[tc].y;
                    const float zg = z[2] + bias[tc].z;
                    const float zo = z[3] + bias[tc].w;
                    const float cn = sigf(zf) * creg[tc][rf] + sigf(zi) * tanh_fast(zg);
                    creg[tc][rf] = cn;
                    const int u = (n0 >> 2) + cq * 16 + tc * 4 + lq;
                    const int b = b0 + rf * 16 + lr;
                    hdst[(size_t)b * 1024 + u] = __float2bfloat16(sigf(zo) * tanh_fast(cn));
                }
        }
        sync_blocks(cnt + grp * 16, 32 * (t + 1));
    }
}

// ---------- final p-GEMM: out[b][t][f] = hist[t][b] @ W_d + b_d ----------
__global__ __launch_bounds__(256) void pgemm(char* ws, float* __restrict__ out,
                                             const float* __restrict__ bd) {
    const int t = blockIdx.x >> 2;
    const int r0 = (blockIdx.x & 3) * 64;
    const int f0 = blockIdx.y * 64;
    const __hip_bfloat16* A = hist_ptr(ws, t);
    const __hip_bfloat16* Bw = (const __hip_bfloat16*)(ws + OWD);

    __shared__ __hip_bfloat16 Al[2][64 * 64];
    __shared__ __hip_bfloat16 Bl[2][64 * 64];

    const int tid = threadIdx.x;
    const int wave = tid >> 6, lane = tid & 63;
    const int whb = (wave >> 1) * 32, wcf = (wave & 1) * 32;
    const int lr = lane & 15, lq = lane >> 4;
    const int l8 = lane >> 3, cb = lane & 7;
    const int gsw = ((cb ^ l8) << 3);
    const int xk = lr & 7;

    f32x4 acc[2][2] = {};
    const int rA0 = whb + lr, rA1 = whb + lr + 16;
    const int rB0 = wcf + lr, rB1 = wcf + lr + 16;

    auto stage = [&](int buf, int k0) {
        #pragma unroll
        for (int l = 0; l < 2; ++l) {
            const int rt = wave * 16 + l * 8;
            const int row = rt + l8;
            gload_lds16(A + (size_t)(r0 + row) * 1024 + k0 + gsw, &Al[buf][rt * 64]);
            gload_lds16(Bw + (size_t)(f0 + row) * 1024 + k0 + gsw, &Bl[buf][rt * 64]);
        }
    };

    stage(0, 0);
    for (int kk = 0; kk < 16; ++kk) {
        const int buf = kk & 1;
        if (kk + 1 < 16) { stage(buf ^ 1, (kk + 1) << 6); asm volatile("s_waitcnt vmcnt(4)" ::: "memory"); }
        else             { asm volatile("s_waitcnt vmcnt(0)" ::: "memory"); }
        SBAR;
        #pragma unroll
        for (int ks = 0; ks < 2; ++ks) {
            const int g0 = ((ks * 4 + lq) ^ xk) << 3;
            bf16x8 a0 = *(const bf16x8*)&Al[buf][rA0 * 64 + g0];
            bf16x8 a1 = *(const bf16x8*)&Al[buf][rA1 * 64 + g0];
            bf16x8 w0 = *(const bf16x8*)&Bl[buf][rB0 * 64 + g0];
            bf16x8 w1 = *(const bf16x8*)&Bl[buf][rB1 * 64 + g0];
            acc[0][0] = __builtin_amdgcn_mfma_f32_16x16x32_bf16(w0, a0, acc[0][0], 0, 0, 0);
            acc[0][1] = __builtin_amdgcn_mfma_f32_16x16x32_bf16(w0, a1, acc[0][1], 0, 0, 0);
            acc[1][0] = __builtin_amdgcn_mfma_f32_16x16x32_bf16(w1, a0, acc[1][0], 0, 0, 0);
            acc[1][1] = __builtin_amdgcn_mfma_f32_16x16x32_bf16(w1, a1, acc[1][1], 0, 0, 0);
        }
        SBAR;
    }
    #pragma unroll
    for (int cf = 0; cf < 2; ++cf) {
        const int fb = f0 + wcf + cf * 16 + lq * 4;
        const float4 b4 = *(const float4*)(bd + fb);
        #pragma unroll
        for (int rf = 0; rf < 2; ++rf) {
            const int b = r0 + whb + rf * 16 + lr;
            float4 o;
            o.x = acc[cf][rf][0] + b4.x;
            o.y = acc[cf][rf][1] + b4.y;
            o.z = acc[cf][rf][2] + b4.z;
            o.w = acc[cf][rf][3] + b4.w;
            *(float4*)(out + (size_t)b * 16384 + (size_t)t * 128 + fb) = o;
        }
    }
}

// ---------- launcher ----------

extern "C" void kernel_launch(void* const* d_in, const int* in_sizes, int n_in,
                              void* d_out, int out_size, void* d_ws, size_t ws_size,
                              hipStream_t stream) {
    const float* inputs = (const float*)d_in[0];
    const float* W_i    = (const float*)d_in[1];
    const float* W_h    = (const float*)d_in[2];
    const float* b      = (const float*)d_in[3];
    const float* W_d    = (const float*)d_in[4];
    const float* b_d    = (const float*)d_in[5];
    float* out = (float*)d_out;
    char* ws = (char*)d_ws;

    hipMemsetAsync(ws + OHP, 0, HSB, stream);      // h(0) = 0
    hipMemsetAsync(ws + OCNT, 0, 1024, stream);    // sync counters

    cvt_bf16<<<8192, 256, 0, stream>>>(inputs, (__hip_bfloat16*)(ws + OX), 256 * 256 * 128);
    build_whwi<<<(1152 * 4096) / 256, 256, 0, stream>>>(
        W_h, W_i, (__hip_bfloat16*)(ws + OWH), (__hip_bfloat16*)(ws + OWI));
    build_wd<<<(128 * 1024) / 256, 256, 0, stream>>>(W_d, (__hip_bfloat16*)(ws + OWD));
    build_bias<<<16, 256, 0, stream>>>(b, b_d, W_i, (float*)(ws + OBR), (float*)(ws + OBF));
    build_wf<<<dim3(64, 16), 256, 0, stream>>>(
        (const __hip_bfloat16*)(ws + OWH), (const __hip_bfloat16*)(ws + OWI),
        W_d, (__hip_bfloat16*)(ws + OWF));

    char* wsp = ws;
    void* ka[] = { &wsp };
    hipLaunchCooperativeKernel((void*)persist, dim3(256), dim3(512), ka, 0, stream);

    pgemm<<<dim3(512, 2), 256, 0, stream>>>(ws, out, b_d);
}

// Round 6
// 2899.716 us; speedup vs baseline: 3.1294x; 3.1294x over previous
//
#include <hip/hip_runtime.h>
#include <hip/hip_bf16.h>

// ---- problem sizes ----
#define UNITS 1024
#define FEATS 128
#define NG    4096
#define NSTEP 383            // 256 warmup + 127 forecast
#define HS    262144         // elems per h slice (256*1024)
#define HSB   524288UL       // bytes per h slice

// ---- ws offsets (bytes) ----
// hist(0) dedicated (written t=255, before the global sync at t==256).
// hist(1..127) written at t>=256 AFTER the global barrier -> overlay dead regions.
#define OX   0UL             // x bf16 [256][256][128]          16,777,216  (hist 1..32)
#define OWH  16777216UL      // WhR [4096][1024] bf16            8,388,608  (hist 33..48)
#define OWI  25165824UL      // WiR [4096][128] bf16             1,048,576  (hist 49..50)
#define OWF  26214400UL      // WfR [4096][1024] bf16            8,388,608  (hist 112..127)
#define OWD  34603008UL      // WdT [128][1024] bf16               262,144
#define OBR  34865152UL      // bias_r [4096] f32                   16,384
#define OBF  34881536UL      // bias_f [4096] f32                   16,384
#define OH0  34897920UL      // hist(0)                            524,288
#define OHP  35422208UL      // hp0, hp1                         1,048,576
#define OHC  36470784UL      // dedicated hist 51..111 (61)     31,981,568
#define OCNT 68452352UL      // sync counters                        1,024

typedef __attribute__((ext_vector_type(8))) short bf16x8;
typedef __attribute__((ext_vector_type(4))) float f32x4;
typedef __attribute__((ext_vector_type(4))) int i32x4;
typedef __attribute__((address_space(3))) char lds_char;
typedef __attribute__((address_space(1))) const char glb_char;

// cached global->LDS (read-only data)
__device__ __forceinline__ void gload_lds16(const void* g, void* l) {
    __builtin_amdgcn_global_load_lds((glb_char*)g, (lds_char*)l, 16, 0, 0);
}
// coherence-point (LLC) global->LDS: sc0|sc1 = bypass L1/L2
__device__ __forceinline__ void gload_lds16_cc(const void* g, void* l) {
    __builtin_amdgcn_global_load_lds((glb_char*)g, (lds_char*)l, 16, 0, 17);
}
// LLC write-through 16B store (ext-vector type -> first-class VGPR quad)
__device__ __forceinline__ void store16_cc(void* p, i32x4 v) {
    asm volatile("global_store_dwordx4 %0, %1, off sc0 sc1" :: "v"(p), "v"(v) : "memory");
}
// LLC-coherent poll load
__device__ __forceinline__ int llc_load(const int* p) {
    int v;
    asm volatile("global_load_dword %0, %1, off sc0 sc1\n\ts_waitcnt vmcnt(0)"
                 : "=v"(v) : "v"(p) : "memory");
    return v;
}

#define CFENCE asm volatile("" ::: "memory")
#define VMCNT0 asm volatile("s_waitcnt vmcnt(0)" ::: "memory")

__device__ __forceinline__ float sigf(float x) { return 1.0f / (1.0f + __expf(-x)); }
__device__ __forceinline__ float tanh_fast(float x) { return 2.0f / (1.0f + __expf(-2.0f * x)) - 1.0f; }

// K-dim permutation (involution, preserves 16-blocks): transpose-within-16
__device__ __forceinline__ int PK(int k) {
    return (k & ~15) | ((k & 3) << 2) | ((k >> 2) & 3);
}

__device__ __forceinline__ __hip_bfloat16* hist_ptr(char* ws, int s) {
    size_t off;
    if (s == 0)        off = OH0;
    else if (s <= 32)  off = OX  + (size_t)(s - 1) * HSB;
    else if (s <= 48)  off = OWH + (size_t)(s - 33) * HSB;
    else if (s <= 50)  off = OWI + (size_t)(s - 49) * HSB;
    else if (s <= 111) off = OHC + (size_t)(s - 51) * HSB;
    else               off = OWF + (size_t)(s - 112) * HSB;
    return (__hip_bfloat16*)(ws + off);
}

// fence-free group barrier: caller drains own stores (vmcnt0) before calling
__device__ __forceinline__ void light_sync(int* c, int target) {
    CFENCE;
    __syncthreads();
    if (threadIdx.x == 0) {
        atomicAdd(c, 1);   // device-scope, relaxed, executes at coherence point
        while (llc_load(c) < target) __builtin_amdgcn_s_sleep(1);
    }
    __syncthreads();
    CFENCE;
}

// ---------- precompute kernels ----------

__global__ void cvt_bf16(const float* __restrict__ in, __hip_bfloat16* __restrict__ out, int n) {
    int i = (blockIdx.x * blockDim.x + threadIdx.x) * 4;
    if (i >= n) return;
    float4 v = *(const float4*)(in + i);
    union { ushort4 u4; __hip_bfloat16 h[4]; } pk;
    pk.h[0] = __float2bfloat16(v.x);
    pk.h[1] = __float2bfloat16(v.y);
    pk.h[2] = __float2bfloat16(v.z);
    pk.h[3] = __float2bfloat16(v.w);
    *(ushort4*)(out + i) = pk.u4;
}

// WhR[j][k] = W_h[PK(k)][col(j)]  (K-dim permuted);  WiR[j][q] = W_i[q][col(j)]
// col(j) = (j&3)*1024 + (j>>2)
__global__ void build_whwi(const float* __restrict__ Wh, const float* __restrict__ Wi,
                           __hip_bfloat16* __restrict__ WhR, __hip_bfloat16* __restrict__ WiR) {
    int idx = blockIdx.x * 256 + threadIdx.x;   // 1152*4096
    int k = idx >> 12, col = idx & 4095;
    int j = ((col & 1023) << 2) | (col >> 10);
    if (k < 1024) WhR[(size_t)j * 1024 + k] = __float2bfloat16(Wh[(size_t)PK(k) * 4096 + col]);
    else          WiR[(size_t)j * 128 + (k - 1024)] = __float2bfloat16(Wi[(size_t)(k - 1024) * 4096 + col]);
}

// WdT[f][k] = W_d[PK(k)][f]
__global__ void build_wd(const float* __restrict__ Wd, __hip_bfloat16* __restrict__ WdT) {
    int idx = blockIdx.x * 256 + threadIdx.x;   // 128*1024
    int f = idx >> 10, k = idx & 1023;
    WdT[(size_t)f * 1024 + k] = __float2bfloat16(Wd[(size_t)PK(k) * 128 + f]);
}

__global__ void build_bias(const float* __restrict__ b, const float* __restrict__ bd,
                           const float* __restrict__ Wi, float* __restrict__ br, float* __restrict__ bf) {
    int j = blockIdx.x * 256 + threadIdx.x;   // 4096
    int col = ((j & 3) << 10) | (j >> 2);
    float base = b[col];
    br[j] = base;
    float v = base;
    for (int q = 0; q < 128; ++q) v += bd[q] * Wi[(size_t)q * 4096 + col];
    bf[j] = v;
}

// WfR[j][k] = WhR[j][k] + sum_q W_d[PK(k)][q] * WiR[j][q]   (all in permuted-k space)
__global__ __launch_bounds__(256) void build_wf(const __hip_bfloat16* __restrict__ WhR,
                                                const __hip_bfloat16* __restrict__ WiR,
                                                const float* __restrict__ Wd,
                                                __hip_bfloat16* __restrict__ WfR) {
    const int j0 = blockIdx.x * 64, k0 = blockIdx.y * 64;
    const int tid = threadIdx.x, wave = tid >> 6, lane = tid & 63;
    const int wj = (wave >> 1) * 32, wk = (wave & 1) * 32;
    const int lr = lane & 15, lq = lane >> 4;
    const int TL = ((lr & 3) << 2) | (lr >> 2);   // P within 16 for A-fragment rows
    f32x4 acc[2][2] = {};
    #pragma unroll
    for (int kc = 0; kc < 4; ++kc) {
        bf16x8 dfr[2], ifr[2];
        #pragma unroll
        for (int q2 = 0; q2 < 2; ++q2) {
            const float* p = Wd + (size_t)(k0 + wk + q2 * 16 + TL) * 128 + kc * 32 + lq * 8;
            __hip_bfloat16* dp = (__hip_bfloat16*)&dfr[q2];
            #pragma unroll
            for (int e = 0; e < 8; ++e) dp[e] = __float2bfloat16(p[e]);
            ifr[q2] = *(const bf16x8*)(WiR + (size_t)(j0 + wj + q2 * 16 + lr) * 128 + kc * 32 + lq * 8);
        }
        acc[0][0] = __builtin_amdgcn_mfma_f32_16x16x32_bf16(dfr[0], ifr[0], acc[0][0], 0, 0, 0);
        acc[0][1] = __builtin_amdgcn_mfma_f32_16x16x32_bf16(dfr[0], ifr[1], acc[0][1], 0, 0, 0);
        acc[1][0] = __builtin_amdgcn_mfma_f32_16x16x32_bf16(dfr[1], ifr[0], acc[1][0], 0, 0, 0);
        acc[1][1] = __builtin_amdgcn_mfma_f32_16x16x32_bf16(dfr[1], ifr[1], acc[1][1], 0, 0, 0);
    }
    #pragma unroll
    for (int cf = 0; cf < 2; ++cf)
        #pragma unroll
        for (int rf = 0; rf < 2; ++rf) {
            const int k = k0 + wk + cf * 16 + lq * 4;
            const int j = j0 + wj + rf * 16 + lr;
            const __hip_bfloat16* whp = WhR + (size_t)j * 1024 + k;
            __hip_bfloat16* wfp = WfR + (size_t)j * 1024 + k;
            #pragma unroll
            for (int e = 0; e < 4; ++e)
                wfp[e] = __float2bfloat16(acc[cf][rf][e] + __bfloat162float(whp[e]));
        }
}

// ---------- persistent LSTM kernel ----------
// Chunk layout: Als[0] = x chunk (warmup only), Als[1+c] = h units [128c,128c+128).
// Round r consumes Als[r]; wait = vmcnt(8-r) (issue order: x, h0..h7).
template<int FIRST>
__device__ __forceinline__ void run_rounds(const __hip_bfloat16 (&Als)[9][32][128],
                                           const bf16x8 (&w)[4][9], f32x4 (&acc)[4][2],
                                           int lr, int lq, int kh) {
    const int sc = ((kh * 4 + lq) ^ lr);
    #pragma unroll
    for (int r = FIRST; r < 9; ++r) {
        asm volatile("s_waitcnt vmcnt(%0)" :: "i"(8 - r) : "memory");
        __builtin_amdgcn_s_barrier();
        CFENCE;
        const bf16x8 a0 = *(const bf16x8*)&Als[r][lr][sc * 8];
        const bf16x8 a1 = *(const bf16x8*)&Als[r][lr + 16][sc * 8];
        #pragma unroll
        for (int tc = 0; tc < 4; ++tc) {
            acc[tc][0] = __builtin_amdgcn_mfma_f32_16x16x32_bf16(w[tc][r], a0, acc[tc][0], 0, 0, 0);
            acc[tc][1] = __builtin_amdgcn_mfma_f32_16x16x32_bf16(w[tc][r], a1, acc[tc][1], 0, 0, 0);
        }
    }
}

__global__ __launch_bounds__(512, 2) void persist(char* ws) {
    const __hip_bfloat16* xb  = (const __hip_bfloat16*)(ws + OX);
    const __hip_bfloat16* whg = (const __hip_bfloat16*)(ws + OWH);
    const __hip_bfloat16* wig = (const __hip_bfloat16*)(ws + OWI);
    const __hip_bfloat16* wfg = (const __hip_bfloat16*)(ws + OWF);
    const float* brg = (const float*)(ws + OBR);
    const float* bfg = (const float*)(ws + OBF);
    __hip_bfloat16* hp0 = (__hip_bfloat16*)(ws + OHP);
    __hip_bfloat16* hp1 = hp0 + HS;
    int* cnt = (int*)(ws + OCNT);

    __shared__ __hip_bfloat16 Als[9][32][128];   // 73728 B staging
    __shared__ float Xl[3][2][4][2][256];        // 49152 B K-split exchange
    __shared__ __hip_bfloat16 hTile[32][32];     //  2048 B h bounce

    const int bid = blockIdx.x;
    const int n0 = (bid & 31) * 128;   // gate-col tile
    const int grp = bid >> 5;          // batch group (8 groups x 32 blocks)
    const int b0 = grp * 32;
    const int ublk = (bid & 31) * 32;  // unit base of this block
    const int tid = threadIdx.x;
    const int wave = tid >> 6, lane = tid & 63;
    const int cq = wave & 1, kh = wave >> 1;     // col 64-group, K-quarter
    const int lr = lane & 15, lq = lane >> 4;

    // weights -> registers (warmup set). w[tc][0]=Wi chunk; w[tc][1+c]=Wh chunk c.
    bf16x8 w[4][9];
    #pragma unroll
    for (int tc = 0; tc < 4; ++tc) {
        const size_t row = (size_t)(n0 + cq * 64 + tc * 16 + lr);
        w[tc][0] = *(const bf16x8*)(wig + row * 128 + kh * 32 + lq * 8);
        #pragma unroll
        for (int c = 0; c < 8; ++c)
            w[tc][1 + c] = *(const bf16x8*)(whg + row * 1024 + c * 128 + kh * 32 + lq * 8);
    }
    float4 bias[4];
    #pragma unroll
    for (int tc = 0; tc < 4; ++tc)
        bias[tc] = *(const float4*)(brg + n0 + cq * 64 + tc * 16 + lq * 4);

    float creg[4][2] = {{0.f,0.f},{0.f,0.f},{0.f,0.f},{0.f,0.f}};

    // staging geometry (inverse-swizzled source, linear LDS dest)
    const int row_s = tid >> 4;
    const int gsw = (((tid & 15) ^ (row_s & 15)) << 3);
    char* sbase = (char*)&Als[0][0][0] + wave * 1024;   // wave-uniform

    for (int t = 0; t < NSTEP; ++t) {
        const bool fc = (t >= 256);
        const __hip_bfloat16* hsrc = fc ? hist_ptr(ws, t - 256) : ((t & 1) ? hp1 : hp0);
        __hip_bfloat16* hdst = (t >= 255) ? hist_ptr(ws, t - 255) : ((t & 1) ? hp0 : hp1);

        if (t == 256) {   // switch to folded forecast weights, then global barrier
            #pragma unroll
            for (int tc = 0; tc < 4; ++tc) {
                const size_t row = (size_t)(n0 + cq * 64 + tc * 16 + lr);
                #pragma unroll
                for (int c = 0; c < 8; ++c)
                    w[tc][1 + c] = *(const bf16x8*)(wfg + row * 1024 + c * 128 + kh * 32 + lq * 8);
                bias[tc] = *(const float4*)(bfg + n0 + cq * 64 + tc * 16 + lq * 4);
            }
            VMCNT0;
            light_sync(cnt + 128, 256);
        }

        // stage: x first (warmup), then h chunks 0..7 (LLC-bypass)
        if (!fc)
            gload_lds16(xb + (size_t)(b0 + row_s) * 32768 + (size_t)t * 128 + gsw, sbase);
        {
            const __hip_bfloat16* hsl = hsrc + (size_t)(b0 + row_s) * 1024 + gsw;
            #pragma unroll
            for (int c = 0; c < 8; ++c)
                gload_lds16_cc(hsl + c * 128, sbase + (1 + c) * 8192);
        }

        f32x4 acc[4][2] = {};
        if (!fc) run_rounds<0>(Als, w, acc, lr, lq, kh);
        else     run_rounds<1>(Als, w, acc, lr, lq, kh);

        // K-split partial exchange
        if (kh != 0) {
            float* xp = &Xl[kh - 1][cq][0][0][0];
            #pragma unroll
            for (int tc = 0; tc < 4; ++tc)
                #pragma unroll
                for (int rf = 0; rf < 2; ++rf)
                    *(f32x4*)(xp + (tc * 2 + rf) * 256 + lane * 4) = acc[tc][rf];
        }
        __syncthreads();

        // cell update (waves 0,1 = kh==0); h -> hTile in permuted-unit order
        if (kh == 0) {
            #pragma unroll
            for (int rf = 0; rf < 2; ++rf) {
                ushort4 hv;
                unsigned short* hvp = (unsigned short*)&hv;
                #pragma unroll
                for (int tc = 0; tc < 4; ++tc) {
                    f32x4 z = acc[tc][rf];
                    #pragma unroll
                    for (int kk = 0; kk < 3; ++kk)
                        z += *(const f32x4*)(&Xl[kk][cq][tc][rf][0] + lane * 4);
                    const float zi = z[0] + bias[tc].x;
                    const float zf = z[1] + bias[tc].y;
                    const float zg = z[2] + bias[tc].z;
                    const float zo = z[3] + bias[tc].w;
                    const float cn = sigf(zf) * creg[tc][rf] + sigf(zi) * tanh_fast(zg);
                    creg[tc][rf] = cn;
                    __hip_bfloat16 hb = __float2bfloat16(sigf(zo) * tanh_fast(cn));
                    hvp[tc] = *(unsigned short*)&hb;
                }
                // permuted local position: P(cq*16 + tc*4 + lq) = cq*16 + lq*4 + tc
                *(ushort4*)&hTile[rf * 16 + lr][cq * 16 + lq * 4] = hv;
            }
        }
        __syncthreads();

        // coalesced LLC write-through of the 32x32 h tile
        if (tid < 128) {
            const int bl = tid >> 2, ch = tid & 3;
            i32x4 v = *(const i32x4*)&hTile[bl][ch * 8];
            store16_cc(hdst + (size_t)(b0 + bl) * 1024 + ublk + ch * 8, v);
        }
        VMCNT0;

        if (t + 1 < NSTEP)
            light_sync(cnt + grp * 16, 32 * (t + 1));
    }
}

// ---------- final p-GEMM: out[b][t][f] = hist[t][b] @ W_d + b_d ----------
__global__ __launch_bounds__(256) void pgemm(char* ws, float* __restrict__ out,
                                             const float* __restrict__ bd) {
    const int t = blockIdx.x >> 2;
    const int r0 = (blockIdx.x & 3) * 64;
    const int f0 = blockIdx.y * 64;
    const __hip_bfloat16* A = hist_ptr(ws, t);
    const __hip_bfloat16* Bw = (const __hip_bfloat16*)(ws + OWD);

    __shared__ __hip_bfloat16 Al[2][64 * 64];
    __shared__ __hip_bfloat16 Bl[2][64 * 64];

    const int tid = threadIdx.x;
    const int wave = tid >> 6, lane = tid & 63;
    const int whb = (wave >> 1) * 32, wcf = (wave & 1) * 32;
    const int lr = lane & 15, lq = lane >> 4;
    const int l8 = lane >> 3, cb = lane & 7;
    const int gsw = ((cb ^ l8) << 3);
    const int xk = lr & 7;

    f32x4 acc[2][2] = {};
    const int rA0 = whb + lr, rA1 = whb + lr + 16;
    const int rB0 = wcf + lr, rB1 = wcf + lr + 16;

    auto stage = [&](int buf, int k0) {
        #pragma unroll
        for (int l = 0; l < 2; ++l) {
            const int rt = wave * 16 + l * 8;
            const int row = rt + l8;
            gload_lds16(A + (size_t)(r0 + row) * 1024 + k0 + gsw, &Al[buf][rt * 64]);
            gload_lds16(Bw + (size_t)(f0 + row) * 1024 + k0 + gsw, &Bl[buf][rt * 64]);
        }
    };

    stage(0, 0);
    for (int kk = 0; kk < 16; ++kk) {
        const int buf = kk & 1;
        if (kk + 1 < 16) { stage(buf ^ 1, (kk + 1) << 6); asm volatile("s_waitcnt vmcnt(4)" ::: "memory"); }
        else             { VMCNT0; }
        CFENCE; __builtin_amdgcn_s_barrier(); CFENCE;
        #pragma unroll
        for (int ks = 0; ks < 2; ++ks) {
            const int g0 = ((ks * 4 + lq) ^ xk) << 3;
            bf16x8 a0 = *(const bf16x8*)&Al[buf][rA0 * 64 + g0];
            bf16x8 a1 = *(const bf16x8*)&Al[buf][rA1 * 64 + g0];
            bf16x8 w0 = *(const bf16x8*)&Bl[buf][rB0 * 64 + g0];
            bf16x8 w1 = *(const bf16x8*)&Bl[buf][rB1 * 64 + g0];
            acc[0][0] = __builtin_amdgcn_mfma_f32_16x16x32_bf16(w0, a0, acc[0][0], 0, 0, 0);
            acc[0][1] = __builtin_amdgcn_mfma_f32_16x16x32_bf16(w0, a1, acc[0][1], 0, 0, 0);
            acc[1][0] = __builtin_amdgcn_mfma_f32_16x16x32_bf16(w1, a0, acc[1][0], 0, 0, 0);
            acc[1][1] = __builtin_amdgcn_mfma_f32_16x16x32_bf16(w1, a1, acc[1][1], 0, 0, 0);
        }
        CFENCE; __builtin_amdgcn_s_barrier(); CFENCE;
    }
    #pragma unroll
    for (int cf = 0; cf < 2; ++cf) {
        const int fb = f0 + wcf + cf * 16 + lq * 4;
        const float4 b4 = *(const float4*)(bd + fb);
        #pragma unroll
        for (int rf = 0; rf < 2; ++rf) {
            const int b = r0 + whb + rf * 16 + lr;
            float4 o;
            o.x = acc[cf][rf][0] + b4.x;
            o.y = acc[cf][rf][1] + b4.y;
            o.z = acc[cf][rf][2] + b4.z;
            o.w = acc[cf][rf][3] + b4.w;
            *(float4*)(out + (size_t)b * 16384 + (size_t)t * 128 + fb) = o;
        }
    }
}

// ---------- launcher ----------

extern "C" void kernel_launch(void* const* d_in, const int* in_sizes, int n_in,
                              void* d_out, int out_size, void* d_ws, size_t ws_size,
                              hipStream_t stream) {
    const float* inputs = (const float*)d_in[0];
    const float* W_i    = (const float*)d_in[1];
    const float* W_h    = (const float*)d_in[2];
    const float* b      = (const float*)d_in[3];
    const float* W_d    = (const float*)d_in[4];
    const float* b_d    = (const float*)d_in[5];
    float* out = (float*)d_out;
    char* ws = (char*)d_ws;

    (void)hipMemsetAsync(ws + OHP, 0, HSB, stream);      // h(0) = 0
    (void)hipMemsetAsync(ws + OCNT, 0, 1024, stream);    // sync counters

    cvt_bf16<<<8192, 256, 0, stream>>>(inputs, (__hip_bfloat16*)(ws + OX), 256 * 256 * 128);
    build_whwi<<<(1152 * 4096) / 256, 256, 0, stream>>>(
        W_h, W_i, (__hip_bfloat16*)(ws + OWH), (__hip_bfloat16*)(ws + OWI));
    build_wd<<<(128 * 1024) / 256, 256, 0, stream>>>(W_d, (__hip_bfloat16*)(ws + OWD));
    build_bias<<<16, 256, 0, stream>>>(b, b_d, W_i, (float*)(ws + OBR), (float*)(ws + OBF));
    build_wf<<<dim3(64, 16), 256, 0, stream>>>(
        (const __hip_bfloat16*)(ws + OWH), (const __hip_bfloat16*)(ws + OWI),
        W_d, (__hip_bfloat16*)(ws + OWF));

    char* wsp = ws;
    void* ka[] = { &wsp };
    (void)hipLaunchCooperativeKernel((void*)persist, dim3(256), dim3(512), ka, 0, stream);

    pgemm<<<dim3(512, 2), 256, 0, stream>>>(ws, out, b_d);
}

// Round 8
// 1833.770 us; speedup vs baseline: 4.9485x; 1.5813x over previous
//
#include <hip/hip_runtime.h>
#include <hip/hip_bf16.h>

// ---- problem sizes ----
#define UNITS 1024
#define FEATS 128
#define NG    4096
#define NSTEP 383            // 256 warmup + 127 forecast
#define HS    262144         // elems per h slice (256*1024)
#define HSB   524288UL       // bytes per h slice

// ---- ws offsets (bytes) ----
// hist(0) dedicated (written t=255, before the global sync at t==256).
// hist(1..127) written at t>=256 AFTER the global barrier -> overlay dead regions.
#define OX   0UL             // x bf16 [256][256][128]          16,777,216  (hist 1..32)
#define OWH  16777216UL      // WhR [4096][1024] bf16            8,388,608  (hist 33..48)
#define OWI  25165824UL      // WiR [4096][128] bf16             1,048,576  (hist 49..50)
#define OWF  26214400UL      // WfR [4096][1024] bf16            8,388,608  (hist 112..127)
#define OWD  34603008UL      // WdT [128][1024] bf16               262,144
#define OBR  34865152UL      // bias_r [4096] f32                   16,384
#define OBF  34881536UL      // bias_f [4096] f32                   16,384
#define OH0  34897920UL      // hist(0)                            524,288
#define OHP  35422208UL      // hp0, hp1                         1,048,576
#define OHC  36470784UL      // dedicated hist 51..111 (61)     31,981,568
#define OCNT 68452352UL      // L2 group counters: 8 x 128B lines
                             // +1024: agent slotc[8] (own line)
                             // +1152: agent global counter (own line)

typedef __attribute__((ext_vector_type(8))) short bf16x8;
typedef __attribute__((ext_vector_type(4))) float f32x4;
typedef __attribute__((ext_vector_type(4))) int i32x4;
typedef __attribute__((address_space(3))) char lds_char;
typedef __attribute__((address_space(1))) const char glb_char;

// cached global->LDS (all staging; L1 freshness handled by buffer_inv)
__device__ __forceinline__ void gload_lds16(const void* g, void* l) {
    __builtin_amdgcn_global_load_lds((glb_char*)g, (lds_char*)l, 16, 0, 0);
}
// LLC-coherent poll load (cross-XCD, R6-proven)
__device__ __forceinline__ int llc_load(const int* p) {
    int v;
    asm volatile("global_load_dword %0, %1, off sc0 sc1\n\ts_waitcnt vmcnt(0)"
                 : "=v"(v) : "v"(p) : "memory");
    return v;
}
// L2-executed atomic inc (no sc1 -> executes at local XCD TCC)
__device__ __forceinline__ void l2_atomic_inc(int* p) {
    int one = 1;
    asm volatile("global_atomic_add %0, %1, off" :: "v"(p), "v"(one) : "memory");
}
// L2-executed atomic poll: add 0, sc0 returns old value (never L1-served)
__device__ __forceinline__ int l2_atomic_poll(int* p) {
    int v; int zero = 0;
    asm volatile("global_atomic_add %0, %1, %2, off sc0\n\ts_waitcnt vmcnt(0)"
                 : "=v"(v) : "v"(p), "v"(zero) : "memory");
    return v;
}

#define CFENCE asm volatile("" ::: "memory")
#define VMCNT0 asm volatile("s_waitcnt vmcnt(0)" ::: "memory")
#define L1INV  asm volatile("buffer_inv" ::: "memory")

__device__ __forceinline__ float sigf(float x) { return 1.0f / (1.0f + __expf(-x)); }
__device__ __forceinline__ float tanh_fast(float x) { return 2.0f / (1.0f + __expf(-2.0f * x)) - 1.0f; }

// K-dim permutation (involution, preserves 16-blocks): transpose-within-16
__device__ __forceinline__ int PK(int k) {
    return (k & ~15) | ((k & 3) << 2) | ((k >> 2) & 3);
}

__device__ __forceinline__ __hip_bfloat16* hist_ptr(char* ws, int s) {
    size_t off;
    if (s == 0)        off = OH0;
    else if (s <= 32)  off = OX  + (size_t)(s - 1) * HSB;
    else if (s <= 48)  off = OWH + (size_t)(s - 33) * HSB;
    else if (s <= 50)  off = OWI + (size_t)(s - 49) * HSB;
    else if (s <= 111) off = OHC + (size_t)(s - 51) * HSB;
    else               off = OWF + (size_t)(s - 112) * HSB;
    return (__hip_bfloat16*)(ws + off);
}

// XCD-local (L2) group barrier: caller drains stores (vmcnt0) first
__device__ __forceinline__ void l2_sync(int* c, int target) {
    CFENCE;
    __syncthreads();
    if (threadIdx.x == 0) {
        l2_atomic_inc(c);
        while (l2_atomic_poll(c) < target) __builtin_amdgcn_s_sleep(1);
    }
    __syncthreads();
    CFENCE;
}

// cross-XCD (LLC) barrier, used once at t==256 (R6-proven mechanism)
__device__ __forceinline__ void llc_sync(int* c, int target) {
    CFENCE;
    __syncthreads();
    if (threadIdx.x == 0) {
        atomicAdd(c, 1);   // device-scope
        while (llc_load(c) < target) __builtin_amdgcn_s_sleep(8);
    }
    __syncthreads();
    CFENCE;
}

// ---------- precompute kernels ----------

__global__ void cvt_bf16(const float* __restrict__ in, __hip_bfloat16* __restrict__ out, int n) {
    int i = (blockIdx.x * blockDim.x + threadIdx.x) * 4;
    if (i >= n) return;
    float4 v = *(const float4*)(in + i);
    union { ushort4 u4; __hip_bfloat16 h[4]; } pk;
    pk.h[0] = __float2bfloat16(v.x);
    pk.h[1] = __float2bfloat16(v.y);
    pk.h[2] = __float2bfloat16(v.z);
    pk.h[3] = __float2bfloat16(v.w);
    *(ushort4*)(out + i) = pk.u4;
}

// WhR[j][k] = W_h[PK(k)][col(j)]  (K-dim permuted);  WiR[j][q] = W_i[q][col(j)]
// col(j) = (j&3)*1024 + (j>>2)
__global__ void build_whwi(const float* __restrict__ Wh, const float* __restrict__ Wi,
                           __hip_bfloat16* __restrict__ WhR, __hip_bfloat16* __restrict__ WiR) {
    int idx = blockIdx.x * 256 + threadIdx.x;   // 1152*4096
    int k = idx >> 12, col = idx & 4095;
    int j = ((col & 1023) << 2) | (col >> 10);
    if (k < 1024) WhR[(size_t)j * 1024 + k] = __float2bfloat16(Wh[(size_t)PK(k) * 4096 + col]);
    else          WiR[(size_t)j * 128 + (k - 1024)] = __float2bfloat16(Wi[(size_t)(k - 1024) * 4096 + col]);
}

// WdT[f][k] = W_d[PK(k)][f]
__global__ void build_wd(const float* __restrict__ Wd, __hip_bfloat16* __restrict__ WdT) {
    int idx = blockIdx.x * 256 + threadIdx.x;   // 128*1024
    int f = idx >> 10, k = idx & 1023;
    WdT[(size_t)f * 1024 + k] = __float2bfloat16(Wd[(size_t)PK(k) * 128 + f]);
}

__global__ void build_bias(const float* __restrict__ b, const float* __restrict__ bd,
                           const float* __restrict__ Wi, float* __restrict__ br, float* __restrict__ bf) {
    int j = blockIdx.x * 256 + threadIdx.x;   // 4096
    int col = ((j & 3) << 10) | (j >> 2);
    float base = b[col];
    br[j] = base;
    float v = base;
    for (int q = 0; q < 128; ++q) v += bd[q] * Wi[(size_t)q * 4096 + col];
    bf[j] = v;
}

// WfR[j][k] = WhR[j][k] + sum_q W_d[PK(k)][q] * WiR[j][q]   (all in permuted-k space)
__global__ __launch_bounds__(256) void build_wf(const __hip_bfloat16* __restrict__ WhR,
                                                const __hip_bfloat16* __restrict__ WiR,
                                                const float* __restrict__ Wd,
                                                __hip_bfloat16* __restrict__ WfR) {
    const int j0 = blockIdx.x * 64, k0 = blockIdx.y * 64;
    const int tid = threadIdx.x, wave = tid >> 6, lane = tid & 63;
    const int wj = (wave >> 1) * 32, wk = (wave & 1) * 32;
    const int lr = lane & 15, lq = lane >> 4;
    const int TL = ((lr & 3) << 2) | (lr >> 2);   // P within 16 for A-fragment rows
    f32x4 acc[2][2] = {};
    #pragma unroll
    for (int kc = 0; kc < 4; ++kc) {
        bf16x8 dfr[2], ifr[2];
        #pragma unroll
        for (int q2 = 0; q2 < 2; ++q2) {
            const float* p = Wd + (size_t)(k0 + wk + q2 * 16 + TL) * 128 + kc * 32 + lq * 8;
            __hip_bfloat16* dp = (__hip_bfloat16*)&dfr[q2];
            #pragma unroll
            for (int e = 0; e < 8; ++e) dp[e] = __float2bfloat16(p[e]);
            ifr[q2] = *(const bf16x8*)(WiR + (size_t)(j0 + wj + q2 * 16 + lr) * 128 + kc * 32 + lq * 8);
        }
        acc[0][0] = __builtin_amdgcn_mfma_f32_16x16x32_bf16(dfr[0], ifr[0], acc[0][0], 0, 0, 0);
        acc[0][1] = __builtin_amdgcn_mfma_f32_16x16x32_bf16(dfr[0], ifr[1], acc[0][1], 0, 0, 0);
        acc[1][0] = __builtin_amdgcn_mfma_f32_16x16x32_bf16(dfr[1], ifr[0], acc[1][0], 0, 0, 0);
        acc[1][1] = __builtin_amdgcn_mfma_f32_16x16x32_bf16(dfr[1], ifr[1], acc[1][1], 0, 0, 0);
    }
    #pragma unroll
    for (int cf = 0; cf < 2; ++cf)
        #pragma unroll
        for (int rf = 0; rf < 2; ++rf) {
            const int k = k0 + wk + cf * 16 + lq * 4;
            const int j = j0 + wj + rf * 16 + lr;
            const __hip_bfloat16* whp = WhR + (size_t)j * 1024 + k;
            __hip_bfloat16* wfp = WfR + (size_t)j * 1024 + k;
            #pragma unroll
            for (int e = 0; e < 4; ++e)
                wfp[e] = __float2bfloat16(acc[cf][rf][e] + __bfloat162float(whp[e]));
        }
}

// ---------- persistent LSTM kernel ----------
__global__ __launch_bounds__(512, 2) void persist(char* ws) {
    const __hip_bfloat16* xb  = (const __hip_bfloat16*)(ws + OX);
    const __hip_bfloat16* whg = (const __hip_bfloat16*)(ws + OWH);
    const __hip_bfloat16* wig = (const __hip_bfloat16*)(ws + OWI);
    const __hip_bfloat16* wfg = (const __hip_bfloat16*)(ws + OWF);
    const float* brg = (const float*)(ws + OBR);
    const float* bfg = (const float*)(ws + OBF);
    __hip_bfloat16* hp0 = (__hip_bfloat16*)(ws + OHP);
    __hip_bfloat16* hp1 = hp0 + HS;

    __shared__ __hip_bfloat16 Als[9][32][128];   // 73728 B staging
    __shared__ float Xl[4][2][4][2][256];        // 65536 B K-split exchange (full)
    __shared__ __hip_bfloat16 hTile[32][32];     //  2048 B h bounce
    __shared__ int claimv[2];

    const int tid = threadIdx.x;

    // ---- physical XCD claim: group = XCD, tile = slot within XCD ----
    if (tid == 0) {
        unsigned xcd;
        asm volatile("s_getreg_b32 %0, hwreg(HW_REG_XCC_ID, 0, 32)" : "=s"(xcd));
        int* slotc = (int*)(ws + OCNT + 1024);
        int slot = atomicAdd(slotc + (xcd & 7), 1);   // agent-scope, own cacheline
        claimv[0] = (int)(xcd & 7);
        claimv[1] = slot & 31;
    }
    __syncthreads();
    const int grp  = claimv[0];         // batch group == physical XCD
    const int tile = claimv[1];         // gate-col tile within group
    const int n0 = tile * 128;
    const int b0 = grp * 32;
    const int ublk = tile * 32;
    int* gcnt = (int*)(ws + OCNT) + grp * 32;       // L2-local line (128B apart)
    int* glc  = (int*)(ws + OCNT + 1152);           // LLC line

    const int wave = tid >> 6, lane = tid & 63;
    const int cq = wave & 1, kh = wave >> 1;     // col 64-group, K-quarter
    const int lr = lane & 15, lq = lane >> 4;

    // weights -> registers (warmup set). w[tc][0]=Wi chunk; w[tc][1+c]=Wh chunk c.
    bf16x8 w[4][9];
    #pragma unroll
    for (int tc = 0; tc < 4; ++tc) {
        const size_t row = (size_t)(n0 + cq * 64 + tc * 16 + lr);
        w[tc][0] = *(const bf16x8*)(wig + row * 128 + kh * 32 + lq * 8);
        #pragma unroll
        for (int c = 0; c < 8; ++c)
            w[tc][1 + c] = *(const bf16x8*)(whg + row * 1024 + c * 128 + kh * 32 + lq * 8);
    }
    // bias quad for the fragments this wave OWNS (tc == kh)
    float4 biasq = *(const float4*)(brg + n0 + cq * 64 + kh * 16 + lq * 4);

    float creg[2] = {0.f, 0.f};   // cell state: unit cq*16+kh*4+lq, batches lr / lr+16

    // staging geometry (inverse-swizzled source, linear LDS dest)
    const int row_s = tid >> 4;
    const int gsw = (((tid & 15) ^ (row_s & 15)) << 3);
    char* sbase = (char*)&Als[0][0][0] + wave * 1024;   // wave-uniform

    // prologue: x(0) prefetch
    gload_lds16(xb + (size_t)(b0 + row_s) * 32768 + gsw, sbase);

    for (int t = 0; t < NSTEP; ++t) {
        const bool fc = (t >= 256);
        const __hip_bfloat16* hsrc = fc ? hist_ptr(ws, t - 256) : ((t & 1) ? hp1 : hp0);
        __hip_bfloat16* hdst = (t >= 255) ? hist_ptr(ws, t - 255) : ((t & 1) ? hp0 : hp1);

        if (t == 256) {   // switch to folded forecast weights, then global barrier
            #pragma unroll
            for (int tc = 0; tc < 4; ++tc) {
                const size_t row = (size_t)(n0 + cq * 64 + tc * 16 + lr);
                #pragma unroll
                for (int c = 0; c < 8; ++c)
                    w[tc][1 + c] = *(const bf16x8*)(wfg + row * 1024 + c * 128 + kh * 32 + lq * 8);
            }
            biasq = *(const float4*)(bfg + n0 + cq * 64 + kh * 16 + lq * 4);
            VMCNT0;
            llc_sync(glc, 256);   // all blocks past warmup before hist overlays x/Wh/Wi/Wf
        }

        // L1 invalidate (h lines may be stale in this CU's L1), then stage h chunks
        L1INV;
        {
            const __hip_bfloat16* hsl = hsrc + (size_t)(b0 + row_s) * 1024 + gsw;
            #pragma unroll
            for (int c = 0; c < 8; ++c)
                gload_lds16(hsl + c * 128, sbase + (1 + c) * 8192);
        }

        // ---- 3 merged rounds of MFMA ----
        f32x4 acc[4][2] = {};
        const int sc = ((kh * 4 + lq) ^ lr);
        {
            auto mf = [&](int r) {
                const bf16x8 a0 = *(const bf16x8*)&Als[r][lr][sc * 8];
                const bf16x8 a1 = *(const bf16x8*)&Als[r][lr + 16][sc * 8];
                #pragma unroll
                for (int tc = 0; tc < 4; ++tc) {
                    acc[tc][0] = __builtin_amdgcn_mfma_f32_16x16x32_bf16(w[tc][r], a0, acc[tc][0], 0, 0, 0);
                    acc[tc][1] = __builtin_amdgcn_mfma_f32_16x16x32_bf16(w[tc][r], a1, acc[tc][1], 0, 0, 0);
                }
            };
            asm volatile("s_waitcnt vmcnt(6)" ::: "memory");
            __builtin_amdgcn_s_barrier(); CFENCE;
            if (!fc) mf(0);
            mf(1); mf(2);
            asm volatile("s_waitcnt vmcnt(3)" ::: "memory");
            __builtin_amdgcn_s_barrier(); CFENCE;
            mf(3); mf(4); mf(5);
            asm volatile("s_waitcnt vmcnt(0)" ::: "memory");
            __builtin_amdgcn_s_barrier(); CFENCE;
            mf(6); mf(7); mf(8);
        }

        // ---- distributed K-split reduce + cell update (owner: tc == kh) ----
        #pragma unroll
        for (int tc = 0; tc < 4; ++tc)
            #pragma unroll
            for (int rf = 0; rf < 2; ++rf)
                *(f32x4*)&Xl[kh][cq][tc][rf][lane * 4] = acc[tc][rf];
        __syncthreads();
        #pragma unroll
        for (int rf = 0; rf < 2; ++rf) {
            f32x4 z = {0.f, 0.f, 0.f, 0.f};
            #pragma unroll
            for (int k2 = 0; k2 < 4; ++k2)
                z += *(const f32x4*)&Xl[k2][cq][kh][rf][lane * 4];
            const float zi = z[0] + biasq.x;
            const float zf = z[1] + biasq.y;
            const float zg = z[2] + biasq.z;
            const float zo = z[3] + biasq.w;
            const float cn = sigf(zf) * creg[rf] + sigf(zi) * tanh_fast(zg);
            creg[rf] = cn;
            // permuted local unit position: P(kh*4+lq) = lq*4+kh
            hTile[rf * 16 + lr][cq * 16 + lq * 4 + kh] = __float2bfloat16(sigf(zo) * tanh_fast(cn));
        }
        __syncthreads();

        // coalesced plain (write-through to local L2) store of the 32x32 h tile
        if (tid < 128) {
            const int bl = tid >> 2, ch = tid & 3;
            *(i32x4*)(hdst + (size_t)(b0 + bl) * 1024 + ublk + ch * 8) =
                *(const i32x4*)&hTile[bl][ch * 8];
        }
        VMCNT0;

        // prefetch next warmup x (immutable, safe pre-barrier)
        if (t + 1 < 256)
            gload_lds16(xb + (size_t)(b0 + row_s) * 32768 + (size_t)(t + 1) * 128 + gsw, sbase);

        if (t + 1 < NSTEP)
            l2_sync(gcnt, 32 * (t + 1));
    }
}

// ---------- final p-GEMM: out[b][t][f] = hist[t][b] @ W_d + b_d ----------
__global__ __launch_bounds__(256) void pgemm(char* ws, float* __restrict__ out,
                                             const float* __restrict__ bd) {
    const int t = blockIdx.x >> 2;
    const int r0 = (blockIdx.x & 3) * 64;
    const int f0 = blockIdx.y * 64;
    const __hip_bfloat16* A = hist_ptr(ws, t);
    const __hip_bfloat16* Bw = (const __hip_bfloat16*)(ws + OWD);

    __shared__ __hip_bfloat16 Al[2][64 * 64];
    __shared__ __hip_bfloat16 Bl[2][64 * 64];

    const int tid = threadIdx.x;
    const int wave = tid >> 6, lane = tid & 63;
    const int whb = (wave >> 1) * 32, wcf = (wave & 1) * 32;
    const int lr = lane & 15, lq = lane >> 4;
    const int l8 = lane >> 3, cb = lane & 7;
    const int gsw = ((cb ^ l8) << 3);
    const int xk = lr & 7;

    f32x4 acc[2][2] = {};
    const int rA0 = whb + lr, rA1 = whb + lr + 16;
    const int rB0 = wcf + lr, rB1 = wcf + lr + 16;

    auto stage = [&](int buf, int k0) {
        #pragma unroll
        for (int l = 0; l < 2; ++l) {
            const int rt = wave * 16 + l * 8;
            const int row = rt + l8;
            gload_lds16(A + (size_t)(r0 + row) * 1024 + k0 + gsw, &Al[buf][rt * 64]);
            gload_lds16(Bw + (size_t)(f0 + row) * 1024 + k0 + gsw, &Bl[buf][rt * 64]);
        }
    };

    stage(0, 0);
    for (int kk = 0; kk < 16; ++kk) {
        const int buf = kk & 1;
        if (kk + 1 < 16) { stage(buf ^ 1, (kk + 1) << 6); asm volatile("s_waitcnt vmcnt(4)" ::: "memory"); }
        else             { VMCNT0; }
        CFENCE; __builtin_amdgcn_s_barrier(); CFENCE;
        #pragma unroll
        for (int ks = 0; ks < 2; ++ks) {
            const int g0 = ((ks * 4 + lq) ^ xk) << 3;
            bf16x8 a0 = *(const bf16x8*)&Al[buf][rA0 * 64 + g0];
            bf16x8 a1 = *(const bf16x8*)&Al[buf][rA1 * 64 + g0];
            bf16x8 w0 = *(const bf16x8*)&Bl[buf][rB0 * 64 + g0];
            bf16x8 w1 = *(const bf16x8*)&Bl[buf][rB1 * 64 + g0];
            acc[0][0] = __builtin_amdgcn_mfma_f32_16x16x32_bf16(w0, a0, acc[0][0], 0, 0, 0);
            acc[0][1] = __builtin_amdgcn_mfma_f32_16x16x32_bf16(w0, a1, acc[0][1], 0, 0, 0);
            acc[1][0] = __builtin_amdgcn_mfma_f32_16x16x32_bf16(w1, a0, acc[1][0], 0, 0, 0);
            acc[1][1] = __builtin_amdgcn_mfma_f32_16x16x32_bf16(w1, a1, acc[1][1], 0, 0, 0);
        }
        CFENCE; __builtin_amdgcn_s_barrier(); CFENCE;
    }
    #pragma unroll
    for (int cf = 0; cf < 2; ++cf) {
        const int fb = f0 + wcf + cf * 16 + lq * 4;
        const float4 b4 = *(const float4*)(bd + fb);
        #pragma unroll
        for (int rf = 0; rf < 2; ++rf) {
            const int b = r0 + whb + rf * 16 + lr;
            float4 o;
            o.x = acc[cf][rf][0] + b4.x;
            o.y = acc[cf][rf][1] + b4.y;
            o.z = acc[cf][rf][2] + b4.z;
            o.w = acc[cf][rf][3] + b4.w;
            *(float4*)(out + (size_t)b * 16384 + (size_t)t * 128 + fb) = o;
        }
    }
}

// ---------- launcher ----------

extern "C" void kernel_launch(void* const* d_in, const int* in_sizes, int n_in,
                              void* d_out, int out_size, void* d_ws, size_t ws_size,
                              hipStream_t stream) {
    const float* inputs = (const float*)d_in[0];
    const float* W_i    = (const float*)d_in[1];
    const float* W_h    = (const float*)d_in[2];
    const float* b      = (const float*)d_in[3];
    const float* W_d    = (const float*)d_in[4];
    const float* b_d    = (const float*)d_in[5];
    float* out = (float*)d_out;
    char* ws = (char*)d_ws;

    (void)hipMemsetAsync(ws + OHP, 0, HSB, stream);      // h(0) = 0
    (void)hipMemsetAsync(ws + OCNT, 0, 2048, stream);    // sync counters + slot claim

    cvt_bf16<<<8192, 256, 0, stream>>>(inputs, (__hip_bfloat16*)(ws + OX), 256 * 256 * 128);
    build_whwi<<<(1152 * 4096) / 256, 256, 0, stream>>>(
        W_h, W_i, (__hip_bfloat16*)(ws + OWH), (__hip_bfloat16*)(ws + OWI));
    build_wd<<<(128 * 1024) / 256, 256, 0, stream>>>(W_d, (__hip_bfloat16*)(ws + OWD));
    build_bias<<<16, 256, 0, stream>>>(b, b_d, W_i, (float*)(ws + OBR), (float*)(ws + OBF));
    build_wf<<<dim3(64, 16), 256, 0, stream>>>(
        (const __hip_bfloat16*)(ws + OWH), (const __hip_bfloat16*)(ws + OWI),
        W_d, (__hip_bfloat16*)(ws + OWF));

    char* wsp = ws;
    void* ka[] = { &wsp };
    (void)hipLaunchCooperativeKernel((void*)persist, dim3(256), dim3(512), ka, 0, stream);

    pgemm<<<dim3(512, 2), 256, 0, stream>>>(ws, out, b_d);
}

// Round 9
// 1757.603 us; speedup vs baseline: 5.1630x; 1.0433x over previous
//
#include <hip/hip_runtime.h>
#include <hip/hip_bf16.h>

// ---- problem sizes ----
#define UNITS 1024
#define FEATS 128
#define NG    4096
#define NSTEP 383            // 256 warmup + 127 forecast
#define HS    262144         // elems per h slice (256*1024)
#define HSB   524288UL       // bytes per h slice

// ---- ws offsets (bytes) ----
// hist(0) dedicated (written t=255, before the global sync at t==256).
// hist(1..127) written at t>=256 AFTER the global barrier -> overlay dead regions.
#define OX   0UL             // x bf16 [256][256][128]          16,777,216  (hist 1..32)
#define OWH  16777216UL      // WhR [4096][1024] bf16            8,388,608  (hist 33..48)
#define OWI  25165824UL      // WiR [4096][128] bf16             1,048,576  (hist 49..50)
#define OWF  26214400UL      // WfR [4096][1024] bf16            8,388,608  (hist 112..127)
#define OWD  34603008UL      // WdT [128][1024] bf16               262,144
#define OBR  34865152UL      // bias_r [4096] f32                   16,384
#define OBF  34881536UL      // bias_f [4096] f32                   16,384
#define OH0  34897920UL      // hist(0)                            524,288
#define OHP  35422208UL      // hp0, hp1                         1,048,576
#define OHC  36470784UL      // dedicated hist 51..111 (61)     31,981,568
#define OCNT 68452352UL      // flags[8 grp][8 chunk] x 128B = 8192
                             // +8192: agent slotc[8] (own line)
                             // +8320: agent global counter (own line)

typedef __attribute__((ext_vector_type(8))) short bf16x8;
typedef __attribute__((ext_vector_type(4))) float f32x4;
typedef __attribute__((ext_vector_type(4))) int i32x4;
typedef __attribute__((address_space(3))) char lds_char;
typedef __attribute__((address_space(1))) const char glb_char;

// cached global->LDS (L1 freshness handled by buffer_inv)
__device__ __forceinline__ void gload_lds16(const void* g, void* l) {
    __builtin_amdgcn_global_load_lds((glb_char*)g, (lds_char*)l, 16, 0, 0);
}
// LLC-coherent poll load (cross-XCD)
__device__ __forceinline__ int llc_load(const int* p) {
    int v;
    asm volatile("global_load_dword %0, %1, off sc0 sc1\n\ts_waitcnt vmcnt(0)"
                 : "=v"(v) : "v"(p) : "memory");
    return v;
}
// L2-executed atomic inc (no sc1 -> executes at local XCD TCC)
__device__ __forceinline__ void l2_atomic_inc(int* p) {
    int one = 1;
    asm volatile("global_atomic_add %0, %1, off" :: "v"(p), "v"(one) : "memory");
}
// L2-executed atomic poll: add 0, sc0 returns old value (never L1-served)
__device__ __forceinline__ int l2_atomic_poll(int* p) {
    int v; int zero = 0;
    asm volatile("global_atomic_add %0, %1, %2, off sc0\n\ts_waitcnt vmcnt(0)"
                 : "=v"(v) : "v"(p), "v"(zero) : "memory");
    return v;
}

#define CFENCE asm volatile("" ::: "memory")
#define VMCNT0 asm volatile("s_waitcnt vmcnt(0)" ::: "memory")
#define L1INV  asm volatile("buffer_inv" ::: "memory")

__device__ __forceinline__ float sigf(float x) { return 1.0f / (1.0f + __expf(-x)); }
__device__ __forceinline__ float tanh_fast(float x) { return 2.0f / (1.0f + __expf(-2.0f * x)) - 1.0f; }

// K-dim permutation (involution, preserves 16-blocks): transpose-within-16
__device__ __forceinline__ int PK(int k) {
    return (k & ~15) | ((k & 3) << 2) | ((k >> 2) & 3);
}

__device__ __forceinline__ __hip_bfloat16* hist_ptr(char* ws, int s) {
    size_t off;
    if (s == 0)        off = OH0;
    else if (s <= 32)  off = OX  + (size_t)(s - 1) * HSB;
    else if (s <= 48)  off = OWH + (size_t)(s - 33) * HSB;
    else if (s <= 50)  off = OWI + (size_t)(s - 49) * HSB;
    else if (s <= 111) off = OHC + (size_t)(s - 51) * HSB;
    else               off = OWF + (size_t)(s - 112) * HSB;
    return (__hip_bfloat16*)(ws + off);
}

// cross-XCD (LLC) barrier, used once at t==256
__device__ __forceinline__ void llc_sync(int* c, int target) {
    CFENCE;
    __syncthreads();
    if (threadIdx.x == 0) {
        atomicAdd(c, 1);   // device-scope
        while (llc_load(c) < target) __builtin_amdgcn_s_sleep(8);
    }
    __syncthreads();
    CFENCE;
}

// ---------- precompute kernels ----------

__global__ void cvt_bf16(const float* __restrict__ in, __hip_bfloat16* __restrict__ out, int n) {
    int i = (blockIdx.x * blockDim.x + threadIdx.x) * 4;
    if (i >= n) return;
    float4 v = *(const float4*)(in + i);
    union { ushort4 u4; __hip_bfloat16 h[4]; } pk;
    pk.h[0] = __float2bfloat16(v.x);
    pk.h[1] = __float2bfloat16(v.y);
    pk.h[2] = __float2bfloat16(v.z);
    pk.h[3] = __float2bfloat16(v.w);
    *(ushort4*)(out + i) = pk.u4;
}

// WhR[j][k] = W_h[PK(k)][col(j)]  (K-dim permuted);  WiR[j][q] = W_i[q][col(j)]
// col(j) = (j&3)*1024 + (j>>2)
__global__ void build_whwi(const float* __restrict__ Wh, const float* __restrict__ Wi,
                           __hip_bfloat16* __restrict__ WhR, __hip_bfloat16* __restrict__ WiR) {
    int idx = blockIdx.x * 256 + threadIdx.x;   // 1152*4096
    int k = idx >> 12, col = idx & 4095;
    int j = ((col & 1023) << 2) | (col >> 10);
    if (k < 1024) WhR[(size_t)j * 1024 + k] = __float2bfloat16(Wh[(size_t)PK(k) * 4096 + col]);
    else          WiR[(size_t)j * 128 + (k - 1024)] = __float2bfloat16(Wi[(size_t)(k - 1024) * 4096 + col]);
}

// WdT[f][k] = W_d[PK(k)][f]
__global__ void build_wd(const float* __restrict__ Wd, __hip_bfloat16* __restrict__ WdT) {
    int idx = blockIdx.x * 256 + threadIdx.x;   // 128*1024
    int f = idx >> 10, k = idx & 1023;
    WdT[(size_t)f * 1024 + k] = __float2bfloat16(Wd[(size_t)PK(k) * 128 + f]);
}

__global__ void build_bias(const float* __restrict__ b, const float* __restrict__ bd,
                           const float* __restrict__ Wi, float* __restrict__ br, float* __restrict__ bf) {
    int j = blockIdx.x * 256 + threadIdx.x;   // 4096
    int col = ((j & 3) << 10) | (j >> 2);
    float base = b[col];
    br[j] = base;
    float v = base;
    for (int q = 0; q < 128; ++q) v += bd[q] * Wi[(size_t)q * 4096 + col];
    bf[j] = v;
}

// WfR[j][k] = WhR[j][k] + sum_q W_d[PK(k)][q] * WiR[j][q]   (all in permuted-k space)
__global__ __launch_bounds__(256) void build_wf(const __hip_bfloat16* __restrict__ WhR,
                                                const __hip_bfloat16* __restrict__ WiR,
                                                const float* __restrict__ Wd,
                                                __hip_bfloat16* __restrict__ WfR) {
    const int j0 = blockIdx.x * 64, k0 = blockIdx.y * 64;
    const int tid = threadIdx.x, wave = tid >> 6, lane = tid & 63;
    const int wj = (wave >> 1) * 32, wk = (wave & 1) * 32;
    const int lr = lane & 15, lq = lane >> 4;
    const int TL = ((lr & 3) << 2) | (lr >> 2);   // P within 16 for A-fragment rows
    f32x4 acc[2][2] = {};
    #pragma unroll
    for (int kc = 0; kc < 4; ++kc) {
        bf16x8 dfr[2], ifr[2];
        #pragma unroll
        for (int q2 = 0; q2 < 2; ++q2) {
            const float* p = Wd + (size_t)(k0 + wk + q2 * 16 + TL) * 128 + kc * 32 + lq * 8;
            __hip_bfloat16* dp = (__hip_bfloat16*)&dfr[q2];
            #pragma unroll
            for (int e = 0; e < 8; ++e) dp[e] = __float2bfloat16(p[e]);
            ifr[q2] = *(const bf16x8*)(WiR + (size_t)(j0 + wj + q2 * 16 + lr) * 128 + kc * 32 + lq * 8);
        }
        acc[0][0] = __builtin_amdgcn_mfma_f32_16x16x32_bf16(dfr[0], ifr[0], acc[0][0], 0, 0, 0);
        acc[0][1] = __builtin_amdgcn_mfma_f32_16x16x32_bf16(dfr[0], ifr[1], acc[0][1], 0, 0, 0);
        acc[1][0] = __builtin_amdgcn_mfma_f32_16x16x32_bf16(dfr[1], ifr[0], acc[1][0], 0, 0, 0);
        acc[1][1] = __builtin_amdgcn_mfma_f32_16x16x32_bf16(dfr[1], ifr[1], acc[1][1], 0, 0, 0);
    }
    #pragma unroll
    for (int cf = 0; cf < 2; ++cf)
        #pragma unroll
        for (int rf = 0; rf < 2; ++rf) {
            const int k = k0 + wk + cf * 16 + lq * 4;
            const int j = j0 + wj + rf * 16 + lr;
            const __hip_bfloat16* whp = WhR + (size_t)j * 1024 + k;
            __hip_bfloat16* wfp = WfR + (size_t)j * 1024 + k;
            #pragma unroll
            for (int e = 0; e < 4; ++e)
                wfp[e] = __float2bfloat16(acc[cf][rf][e] + __bfloat162float(whp[e]));
        }
}

// ---------- persistent LSTM kernel (dataflow flags, no per-step group barrier) ----------
__global__ __launch_bounds__(512, 2) void persist(char* ws) {
    const __hip_bfloat16* xb  = (const __hip_bfloat16*)(ws + OX);
    const __hip_bfloat16* whg = (const __hip_bfloat16*)(ws + OWH);
    const __hip_bfloat16* wig = (const __hip_bfloat16*)(ws + OWI);
    const __hip_bfloat16* wfg = (const __hip_bfloat16*)(ws + OWF);
    const float* brg = (const float*)(ws + OBR);
    const float* bfg = (const float*)(ws + OBF);
    __hip_bfloat16* hp0 = (__hip_bfloat16*)(ws + OHP);
    __hip_bfloat16* hp1 = hp0 + HS;

    __shared__ __hip_bfloat16 Als[9][32][128];   // 73728 B staging
    __shared__ float Xl[4][2][4][2][256];        // 65536 B K-split exchange
    __shared__ __hip_bfloat16 hTile[32][32];     //  2048 B h bounce
    __shared__ int claimv[2];
    __shared__ int rdy[16];                      // per-chunk LDS ready flags (monotone)

    const int tid = threadIdx.x;

    // ---- physical XCD claim: group = XCD, tile = slot within XCD ----
    if (tid < 16) rdy[tid] = 0;
    if (tid == 0) {
        unsigned xcd;
        asm volatile("s_getreg_b32 %0, hwreg(HW_REG_XCC_ID, 0, 32)" : "=s"(xcd));
        int* slotc = (int*)(ws + OCNT + 8192);
        int slot = atomicAdd(slotc + (xcd & 7), 1);   // agent-scope, own cacheline
        claimv[0] = (int)(xcd & 7);
        claimv[1] = slot & 31;
    }
    __syncthreads();
    const int grp  = claimv[0];         // batch group == physical XCD
    const int tile = claimv[1];         // gate-col tile within group
    const int n0 = tile * 128;
    const int b0 = grp * 32;
    const int ublk = tile * 32;
    int* fbase = (int*)(ws + OCNT + (size_t)grp * 1024);   // flags[grp][c] at +c*128B
    int* glc   = (int*)(ws + OCNT + 8320);                 // LLC line

    const int wave = tid >> 6, lane = tid & 63;
    const int cq = wave & 1, kh = wave >> 1;     // col 64-group, K-quarter
    const int lr = lane & 15, lq = lane >> 4;

    // weights -> registers (warmup set). w[tc][0]=Wi chunk; w[tc][1+c]=Wh chunk c.
    bf16x8 w[4][9];
    #pragma unroll
    for (int tc = 0; tc < 4; ++tc) {
        const size_t row = (size_t)(n0 + cq * 64 + tc * 16 + lr);
        w[tc][0] = *(const bf16x8*)(wig + row * 128 + kh * 32 + lq * 8);
        #pragma unroll
        for (int c = 0; c < 8; ++c)
            w[tc][1 + c] = *(const bf16x8*)(whg + row * 1024 + c * 128 + kh * 32 + lq * 8);
    }
    // bias quad for the fragments this wave OWNS (tc == kh)
    float4 biasq = *(const float4*)(brg + n0 + cq * 64 + kh * 16 + lq * 4);

    float creg[2] = {0.f, 0.f};   // cell state: unit cq*16+kh*4+lq, batches lr / lr+16

    // prologue: wave 0 prefetches x(0) into Als[0]
    if (wave == 0) {
        #pragma unroll
        for (int j = 0; j < 8; ++j) {
            const int r32 = j * 4 + lq;
            const int ce = ((lane & 15) ^ (r32 & 15)) << 3;
            gload_lds16(xb + (size_t)(b0 + r32) * 32768 + ce,
                        (char*)&Als[0][0][0] + j * 1024);
        }
    }

    for (int t = 0; t < NSTEP; ++t) {
        const bool fc = (t >= 256);
        const __hip_bfloat16* hsrc = fc ? hist_ptr(ws, t - 256) : ((t & 1) ? hp1 : hp0);
        __hip_bfloat16* hdst = (t >= 255) ? hist_ptr(ws, t - 255) : ((t & 1) ? hp0 : hp1);

        if (t == 256) {   // switch to folded forecast weights, then one global barrier
            #pragma unroll
            for (int tc = 0; tc < 4; ++tc) {
                const size_t row = (size_t)(n0 + cq * 64 + tc * 16 + lr);
                #pragma unroll
                for (int c = 0; c < 8; ++c)
                    w[tc][1 + c] = *(const bf16x8*)(wfg + row * 1024 + c * 128 + kh * 32 + lq * 8);
            }
            biasq = *(const float4*)(bfg + n0 + cq * 64 + kh * 16 + lq * 4);
            VMCNT0;
            llc_sync(glc, 256);   // all blocks past warmup before hist overlays x/Wh/Wi/Wf
        }

        // ---- per-chunk producer flag wait, then stage OWN chunk (wave w -> chunk w) ----
        if (t > 0 && lane == 0) {
            int* fl = fbase + wave * 32;
            while (l2_atomic_poll(fl) < 4 * t) __builtin_amdgcn_s_sleep(1);
        }
        L1INV;
        {
            const __hip_bfloat16* srcb = hsrc + (size_t)b0 * 1024 + wave * 128;
            char* dstc = (char*)&Als[1 + wave][0][0];
            #pragma unroll
            for (int j = 0; j < 8; ++j) {
                const int r32 = j * 4 + lq;
                const int ce = ((lane & 15) ^ (r32 & 15)) << 3;
                gload_lds16(srcb + (size_t)r32 * 1024 + ce, dstc + j * 1024);
            }
        }
        VMCNT0;   // also covers wave 0's x prefetch
        __hip_atomic_store(&rdy[wave], t + 1, __ATOMIC_RELEASE, __HIP_MEMORY_SCOPE_WORKGROUP);

        // ---- compute: 9 rounds, each gated on its chunk's LDS ready flag ----
        f32x4 acc[4][2] = {};
        const int sc = ((kh * 4 + lq) ^ lr);
        auto wr_ = [&](int p) {
            while (__hip_atomic_load(&rdy[p], __ATOMIC_ACQUIRE, __HIP_MEMORY_SCOPE_WORKGROUP) < t + 1) {}
            __builtin_amdgcn_sched_barrier(0);
        };
        auto mfr = [&](int r) {
            const bf16x8 a0 = *(const bf16x8*)&Als[r][lr][sc * 8];
            const bf16x8 a1 = *(const bf16x8*)&Als[r][lr + 16][sc * 8];
            #pragma unroll
            for (int tc = 0; tc < 4; ++tc) {
                acc[tc][0] = __builtin_amdgcn_mfma_f32_16x16x32_bf16(w[tc][r], a0, acc[tc][0], 0, 0, 0);
                acc[tc][1] = __builtin_amdgcn_mfma_f32_16x16x32_bf16(w[tc][r], a1, acc[tc][1], 0, 0, 0);
            }
        };
        if (!fc) { wr_(0); mfr(0); }
        #pragma unroll
        for (int r = 1; r <= 8; ++r) { wr_(r - 1); mfr(r); }

        // ---- distributed K-split reduce + cell update (owner: tc == kh) ----
        #pragma unroll
        for (int tc = 0; tc < 4; ++tc)
            #pragma unroll
            for (int rf = 0; rf < 2; ++rf)
                *(f32x4*)&Xl[kh][cq][tc][rf][lane * 4] = acc[tc][rf];
        __syncthreads();
        #pragma unroll
        for (int rf = 0; rf < 2; ++rf) {
            f32x4 z = {0.f, 0.f, 0.f, 0.f};
            #pragma unroll
            for (int k2 = 0; k2 < 4; ++k2)
                z += *(const f32x4*)&Xl[k2][cq][kh][rf][lane * 4];
            const float zi = z[0] + biasq.x;
            const float zf = z[1] + biasq.y;
            const float zg = z[2] + biasq.z;
            const float zo = z[3] + biasq.w;
            const float cn = sigf(zf) * creg[rf] + sigf(zi) * tanh_fast(zg);
            creg[rf] = cn;
            // permuted local unit position: P(kh*4+lq) = lq*4+kh
            hTile[rf * 16 + lr][cq * 16 + lq * 4 + kh] = __float2bfloat16(sigf(zo) * tanh_fast(cn));
        }
        __syncthreads();

        // ---- coalesced store of the 32x32 h tile, drain, publish ----
        if (tid < 128) {
            const int bl = tid >> 2, ch = tid & 3;
            *(i32x4*)(hdst + (size_t)(b0 + bl) * 1024 + ublk + ch * 8) =
                *(const i32x4*)&hTile[bl][ch * 8];
        }
        VMCNT0;
        __syncthreads();   // all stores drained block-wide
        if (tid == 0) l2_atomic_inc(fbase + (tile >> 2) * 32);

        // prefetch next warmup x into Als[0] (safe: all compute done)
        if (wave == 0 && t + 1 < 256) {
            #pragma unroll
            for (int j = 0; j < 8; ++j) {
                const int r32 = j * 4 + lq;
                const int ce = ((lane & 15) ^ (r32 & 15)) << 3;
                gload_lds16(xb + (size_t)(b0 + r32) * 32768 + (size_t)(t + 1) * 128 + ce,
                            (char*)&Als[0][0][0] + j * 1024);
            }
        }
    }
}

// ---------- final p-GEMM: out[b][t][f] = hist[t][b] @ W_d + b_d ----------
__global__ __launch_bounds__(256) void pgemm(char* ws, float* __restrict__ out,
                                             const float* __restrict__ bd) {
    const int t = blockIdx.x >> 2;
    const int r0 = (blockIdx.x & 3) * 64;
    const int f0 = blockIdx.y * 64;
    const __hip_bfloat16* A = hist_ptr(ws, t);
    const __hip_bfloat16* Bw = (const __hip_bfloat16*)(ws + OWD);

    __shared__ __hip_bfloat16 Al[2][64 * 64];
    __shared__ __hip_bfloat16 Bl[2][64 * 64];

    const int tid = threadIdx.x;
    const int wave = tid >> 6, lane = tid & 63;
    const int whb = (wave >> 1) * 32, wcf = (wave & 1) * 32;
    const int lr = lane & 15, lq = lane >> 4;
    const int l8 = lane >> 3, cb = lane & 7;
    const int gsw = ((cb ^ l8) << 3);
    const int xk = lr & 7;

    f32x4 acc[2][2] = {};
    const int rA0 = whb + lr, rA1 = whb + lr + 16;
    const int rB0 = wcf + lr, rB1 = wcf + lr + 16;

    auto stage = [&](int buf, int k0) {
        #pragma unroll
        for (int l = 0; l < 2; ++l) {
            const int rt = wave * 16 + l * 8;
            const int row = rt + l8;
            gload_lds16(A + (size_t)(r0 + row) * 1024 + k0 + gsw, &Al[buf][rt * 64]);
            gload_lds16(Bw + (size_t)(f0 + row) * 1024 + k0 + gsw, &Bl[buf][rt * 64]);
        }
    };

    stage(0, 0);
    for (int kk = 0; kk < 16; ++kk) {
        const int buf = kk & 1;
        if (kk + 1 < 16) { stage(buf ^ 1, (kk + 1) << 6); asm volatile("s_waitcnt vmcnt(4)" ::: "memory"); }
        else             { VMCNT0; }
        CFENCE; __builtin_amdgcn_s_barrier(); CFENCE;
        #pragma unroll
        for (int ks = 0; ks < 2; ++ks) {
            const int g0 = ((ks * 4 + lq) ^ xk) << 3;
            bf16x8 a0 = *(const bf16x8*)&Al[buf][rA0 * 64 + g0];
            bf16x8 a1 = *(const bf16x8*)&Al[buf][rA1 * 64 + g0];
            bf16x8 w0 = *(const bf16x8*)&Bl[buf][rB0 * 64 + g0];
            bf16x8 w1 = *(const bf16x8*)&Bl[buf][rB1 * 64 + g0];
            acc[0][0] = __builtin_amdgcn_mfma_f32_16x16x32_bf16(w0, a0, acc[0][0], 0, 0, 0);
            acc[0][1] = __builtin_amdgcn_mfma_f32_16x16x32_bf16(w0, a1, acc[0][1], 0, 0, 0);
            acc[1][0] = __builtin_amdgcn_mfma_f32_16x16x32_bf16(w1, a0, acc[1][0], 0, 0, 0);
            acc[1][1] = __builtin_amdgcn_mfma_f32_16x16x32_bf16(w1, a1, acc[1][1], 0, 0, 0);
        }
        CFENCE; __builtin_amdgcn_s_barrier(); CFENCE;
    }
    #pragma unroll
    for (int cf = 0; cf < 2; ++cf) {
        const int fb = f0 + wcf + cf * 16 + lq * 4;
        const float4 b4 = *(const float4*)(bd + fb);
        #pragma unroll
        for (int rf = 0; rf < 2; ++rf) {
            const int b = r0 + whb + rf * 16 + lr;
            float4 o;
            o.x = acc[cf][rf][0] + b4.x;
            o.y = acc[cf][rf][1] + b4.y;
            o.z = acc[cf][rf][2] + b4.z;
            o.w = acc[cf][rf][3] + b4.w;
            *(float4*)(out + (size_t)b * 16384 + (size_t)t * 128 + fb) = o;
        }
    }
}

// ---------- launcher ----------

extern "C" void kernel_launch(void* const* d_in, const int* in_sizes, int n_in,
                              void* d_out, int out_size, void* d_ws, size_t ws_size,
                              hipStream_t stream) {
    const float* inputs = (const float*)d_in[0];
    const float* W_i    = (const float*)d_in[1];
    const float* W_h    = (const float*)d_in[2];
    const float* b      = (const float*)d_in[3];
    const float* W_d    = (const float*)d_in[4];
    const float* b_d    = (const float*)d_in[5];
    float* out = (float*)d_out;
    char* ws = (char*)d_ws;

    (void)hipMemsetAsync(ws + OHP, 0, HSB, stream);      // h(0) = 0
    (void)hipMemsetAsync(ws + OCNT, 0, 16384, stream);   // flags + slot claim + global counter

    cvt_bf16<<<8192, 256, 0, stream>>>(inputs, (__hip_bfloat16*)(ws + OX), 256 * 256 * 128);
    build_whwi<<<(1152 * 4096) / 256, 256, 0, stream>>>(
        W_h, W_i, (__hip_bfloat16*)(ws + OWH), (__hip_bfloat16*)(ws + OWI));
    build_wd<<<(128 * 1024) / 256, 256, 0, stream>>>(W_d, (__hip_bfloat16*)(ws + OWD));
    build_bias<<<16, 256, 0, stream>>>(b, b_d, W_i, (float*)(ws + OBR), (float*)(ws + OBF));
    build_wf<<<dim3(64, 16), 256, 0, stream>>>(
        (const __hip_bfloat16*)(ws + OWH), (const __hip_bfloat16*)(ws + OWI),
        W_d, (__hip_bfloat16*)(ws + OWF));

    char* wsp = ws;
    void* ka[] = { &wsp };
    (void)hipLaunchCooperativeKernel((void*)persist, dim3(256), dim3(512), ka, 0, stream);

    pgemm<<<dim3(512, 2), 256, 0, stream>>>(ws, out, b_d);
}